// Round 3
// baseline (2780.280 us; speedup 1.0000x reference)
//
#include <hip/hip_runtime.h>
#include <hip/hip_bf16.h>
#include <stdint.h>

typedef __attribute__((ext_vector_type(8))) __bf16 bf16x8;
typedef __attribute__((ext_vector_type(8))) short short8;
typedef __attribute__((ext_vector_type(4))) float floatx4;
using bf16 = __hip_bfloat16;

#define DEVINL __device__ __forceinline__

typedef __attribute__((address_space(1))) const void gconst_void;
typedef __attribute__((address_space(3))) void lds_void;

DEVINL void gl2lds16(const void* g, void* l) {
    __builtin_amdgcn_global_load_lds((gconst_void*)g, (lds_void*)l, 16, 0, 0);
}

DEVINL unsigned short f2us(float x) {
    bf16 h = __float2bfloat16(x);
    return __builtin_bit_cast(unsigned short, h);
}
// flag==1: inputs are f32; flag==0: inputs are bf16
DEVINL float ld_in(const void* p, int f, size_t i) {
    return f ? ((const float*)p)[i] : __bfloat162float(((const bf16*)p)[i]);
}

// ---------------- dtype probe ----------------
// Read first 64 words of coarse_m AS f32. True f32 N(0,1): |x| in (1e-8,100) ~always.
// bf16-pairs as f32: exponent >= ~220 (astronomical) or denormal -> fails test.
__global__ void detect_k(const void* x, int* flag) {
    if (threadIdx.x == 0) {
        const float* xf = (const float*)x;
        int good = 0;
        for (int i = 0; i < 64; i++) {
            float a = fabsf(xf[i]);
            if (a > 1e-8f && a < 100.f) good++;
        }
        *flag = (good >= 48) ? 1 : 0;
    }
}

// ---------------- prep kernels ----------------

// zero the 1-wide spatial border of a padded (G,66,66,C) NHWC buffer
__global__ void zero_border_k(bf16* buf, int C) {
    int cell = blockIdx.x;   // 0..259
    int b = blockIdx.y;      // local image
    int hp, wp;
    if (cell < 66)       { hp = 0;          wp = cell; }
    else if (cell < 132) { hp = 65;         wp = cell - 66; }
    else if (cell < 196) { hp = cell - 131; wp = 0; }
    else                 { hp = cell - 195; wp = 65; }
    unsigned short* p = (unsigned short*)buf + (size_t)(b * 4356 + hp * 66 + wp) * C;
    for (int c = threadIdx.x; c < C; c += 256) p[c] = 0;
}

// NCHW (B,Csrc,64,64) image (b0+bz) -> padded NHWC interior (local bz) at channel offset
__global__ void nchw_to_pnhwc_k(const void* __restrict__ src, bf16* __restrict__ dst,
                                const int* __restrict__ flag,
                                int Csrc, int dstC, int chanOff, int b0) {
    __shared__ unsigned short t[32][72];
    int c0 = blockIdx.x * 32, h = blockIdx.y, bz = blockIdx.z;
    int tid = threadIdx.x;
    {
        int c = tid >> 3, w8 = (tid & 7) * 8;
        size_t base = (((size_t)((b0 + bz) * Csrc + c0 + c)) * 64 + h) * 64 + w8;
        unsigned short* tp = &t[c][w8];
        if (*flag) {
            const float* sf = (const float*)src;
            float4 v0 = *(const float4*)(sf + base);
            float4 v1 = *(const float4*)(sf + base + 4);
            tp[0] = f2us(v0.x); tp[1] = f2us(v0.y); tp[2] = f2us(v0.z); tp[3] = f2us(v0.w);
            tp[4] = f2us(v1.x); tp[5] = f2us(v1.y); tp[6] = f2us(v1.z); tp[7] = f2us(v1.w);
        } else {
            uint4 v = *(const uint4*)((const unsigned short*)src + base);
            *(uint4*)tp = v;
        }
    }
    __syncthreads();
    {
        int w = tid >> 2, cq = (tid & 3) * 8;
        uint32_t p0 = t[cq + 0][w] | ((uint32_t)t[cq + 1][w] << 16);
        uint32_t p1 = t[cq + 2][w] | ((uint32_t)t[cq + 3][w] << 16);
        uint32_t p2 = t[cq + 4][w] | ((uint32_t)t[cq + 5][w] << 16);
        uint32_t p3 = t[cq + 6][w] | ((uint32_t)t[cq + 7][w] << 16);
        uint4 o; o.x = p0; o.y = p1; o.z = p2; o.w = p3;
        size_t off = ((size_t)(bz * 4356 + (h + 1) * 66 + (w + 1))) * dstC + chanOff + c0 + cq;
        *(uint4*)((unsigned short*)dst + off) = o;
    }
}

// raw_x (B,3,512,512) image (b0+bz) -> Xa channels [384+craw*64+gy*8+gx] (craw-major)
__global__ void raw_patches_k(const void* __restrict__ raw, bf16* __restrict__ Xa,
                              const int* __restrict__ flag, int b0) {
    __shared__ unsigned short t[8][520];
    int h = blockIdx.x, craw = blockIdx.y, bz = blockIdx.z;
    int tid = threadIdx.x;
    int f = *flag;
#pragma unroll
    for (int k = 0; k < 2; k++) {
        int s = tid + k * 256;
        int gy = s >> 6, seg = s & 63;
        size_t base = (((size_t)((b0 + bz) * 3 + craw) * 512) + gy * 64 + h) * 512 + seg * 8;
        unsigned short* tp = &t[gy][seg * 8];
        if (f) {
            const float* rf = (const float*)raw;
            float4 v0 = *(const float4*)(rf + base);
            float4 v1 = *(const float4*)(rf + base + 4);
            tp[0] = f2us(v0.x); tp[1] = f2us(v0.y); tp[2] = f2us(v0.z); tp[3] = f2us(v0.w);
            tp[4] = f2us(v1.x); tp[5] = f2us(v1.y); tp[6] = f2us(v1.z); tp[7] = f2us(v1.w);
        } else {
            uint4 v = *(const uint4*)((const unsigned short*)raw + base);
            *(uint4*)tp = v;
        }
    }
    __syncthreads();
#pragma unroll
    for (int k = 0; k < 2; k++) {
        int s = tid + k * 256;
        int w = s >> 3, gq = s & 7;
        uint32_t p0 = t[gq][0 * 64 + w] | ((uint32_t)t[gq][1 * 64 + w] << 16);
        uint32_t p1 = t[gq][2 * 64 + w] | ((uint32_t)t[gq][3 * 64 + w] << 16);
        uint32_t p2 = t[gq][4 * 64 + w] | ((uint32_t)t[gq][5 * 64 + w] << 16);
        uint32_t p3 = t[gq][6 * 64 + w] | ((uint32_t)t[gq][7 * 64 + w] << 16);
        uint4 o; o.x = p0; o.y = p1; o.z = p2; o.w = p3;
        size_t off = ((size_t)(bz * 4356 + (h + 1) * 66 + (w + 1))) * 576 + 384 + craw * 64 + gq * 8;
        *(uint4*)((unsigned short*)Xa + off) = o;
    }
}

// W[co][ci][3][3] -> Wp[kk][co_pad640][ci]; remap=1 permutes dec ci to craw-major order
__global__ void fold_w_k(const void* __restrict__ W, bf16* __restrict__ dst,
                         const int* __restrict__ flag, int Cin, int remap) {
    int ci = blockIdx.x * 256 + threadIdx.x;
    if (ci >= Cin) return;
    int co = blockIdx.y;  // 0..639
    int kk = blockIdx.z;  // 0..8
    unsigned short out = 0;
    if (co < 576) {
        int oc = ci;
        if (remap && ci >= 384) {
            int tt = ci - 384;
            int craw = tt >> 6, gy = (tt >> 3) & 7, gx = tt & 7;
            oc = 384 + gy * 24 + gx * 3 + craw;
        }
        size_t sidx = ((size_t)co * Cin + oc) * 9 + kk;
        out = (*flag) ? f2us(((const float*)W)[sidx]) : ((const unsigned short*)W)[sidx];
    }
    ((unsigned short*)dst)[((size_t)kk * 640 + co) * Cin + ci] = out;
}

// per-channel BN fold: inv = g/sqrt(v+eps), beta = b - m*inv
__global__ void scale_beta_k(const void* g, const void* b, const void* m, const void* v,
                             const int* __restrict__ flag, float* inv_out, float* beta_out) {
    int i = blockIdx.x * 256 + threadIdx.x;
    int f = *flag;
    if (i < 576) {
        float inv = ld_in(g, f, i) / sqrtf(ld_in(v, f, i) + 1e-5f);
        inv_out[i] = inv;
        beta_out[i] = ld_in(b, f, i) - ld_in(m, f, i) * inv;
    }
}

// ---------------- 3x3 conv as implicit GEMM (m97 structure), M = gridDim.x*128 ----------------
__global__ __launch_bounds__(256)
void conv3x3_mfma(const bf16* __restrict__ X, const bf16* __restrict__ Wp,
                  const float* __restrict__ inv, const float* __restrict__ beta,
                  bf16* __restrict__ dst, int Cin, int dstC, int chanOff, int dstPadded) {
    __shared__ __align__(16) bf16 Alds[128 * 32];
    __shared__ __align__(16) bf16 Blds[128 * 32];
    const int tid = threadIdx.x;
    const int wv = tid >> 6;
    const int lane = tid & 63;
    const int quad = lane >> 4;
    const int r16 = lane & 15;
    const int m0 = blockIdx.x * 128;
    const int n0 = blockIdx.y * 128;

    const int arow = tid >> 2;
    const int ach = (tid & 3) * 8;
    int abase1, abase2;
    {
        int r = m0 + arow;
        int bb = r >> 12, hh = (r >> 6) & 63, ww = r & 63;
        abase1 = (bb * 4356 + (hh + 1) * 66 + (ww + 1)) * Cin + ach;
        r += 64;
        bb = r >> 12; hh = (r >> 6) & 63; ww = r & 63;
        abase2 = (bb * 4356 + (hh + 1) * 66 + (ww + 1)) * Cin + ach;
    }
    const int bbase1 = (n0 + arow) * Cin + ach;
    const int bbase2 = bbase1 + 64 * Cin;

    bf16* aldsW1 = Alds + wv * 512;          // wave-uniform LDS base (HW adds lane*16B)
    bf16* aldsW2 = Alds + 2048 + wv * 512;
    bf16* bldsW1 = Blds + wv * 512;
    bf16* bldsW2 = Blds + 2048 + wv * 512;

    floatx4 acc[4][4];
    floatx4 zero = {0.f, 0.f, 0.f, 0.f};
#pragma unroll
    for (int i = 0; i < 4; i++)
#pragma unroll
        for (int j = 0; j < 4; j++) acc[i][j] = zero;

    const int mh = (wv & 1) * 64;
    const int nh = (wv >> 1) * 64;

    for (int kk = 0; kk < 9; kk++) {
        const int dh = kk / 3 - 1, dw = kk % 3 - 1;
        const int tap = (dh * 66 + dw) * Cin;
        const bf16* Ag1 = X + abase1 + tap;
        const bf16* Ag2 = X + abase2 + tap;
        const bf16* Bg1 = Wp + (size_t)kk * 640 * Cin + bbase1;
        const bf16* Bg2 = Wp + (size_t)kk * 640 * Cin + bbase2;
        for (int ci = 0; ci < Cin; ci += 32) {
            __syncthreads();
            gl2lds16(Ag1 + ci, aldsW1);
            gl2lds16(Ag2 + ci, aldsW2);
            gl2lds16(Bg1 + ci, bldsW1);
            gl2lds16(Bg2 + ci, bldsW2);
            __syncthreads();                  // vmcnt drained at barrier
            short8 af[4], bfr[4];
#pragma unroll
            for (int i = 0; i < 4; i++)
                af[i] = *(const short8*)(Alds + (mh + i * 16 + r16) * 32 + quad * 8);
#pragma unroll
            for (int j = 0; j < 4; j++)
                bfr[j] = *(const short8*)(Blds + (nh + j * 16 + r16) * 32 + quad * 8);
#pragma unroll
            for (int i = 0; i < 4; i++)
#pragma unroll
                for (int j = 0; j < 4; j++)
                    acc[i][j] = __builtin_amdgcn_mfma_f32_16x16x32_bf16(
                        __builtin_bit_cast(bf16x8, af[i]), __builtin_bit_cast(bf16x8, bfr[j]),
                        acc[i][j], 0, 0, 0);
        }
    }

    // epilogue: D[row=quad*4+r, col=lane&15] (verified m89/m91 layout)
    int ncol[4]; float sj[4], bj[4]; bool nval[4];
#pragma unroll
    for (int j = 0; j < 4; j++) {
        ncol[j] = n0 + nh + j * 16 + r16;
        nval[j] = ncol[j] < 576;
        sj[j] = nval[j] ? inv[ncol[j]] : 0.f;
        bj[j] = nval[j] ? beta[ncol[j]] : 0.f;
    }
#pragma unroll
    for (int i = 0; i < 4; i++) {
#pragma unroll
        for (int r = 0; r < 4; r++) {
            int row = m0 + mh + i * 16 + quad * 4 + r;
            int didx;
            if (dstPadded) {
                int bb = row >> 12, hh = (row >> 6) & 63, ww = row & 63;
                didx = (bb * 4356 + (hh + 1) * 66 + (ww + 1)) * dstC + chanOff;
            } else {
                didx = row * dstC + chanOff;
            }
#pragma unroll
            for (int j = 0; j < 4; j++)
                if (nval[j]) dst[didx + ncol[j]] = __float2bfloat16(acc[i][j][r] * sj[j] + bj[j]);
        }
    }
}

// ---------------- tail: 1x1 conv (576->1) + x8 bilinear upsample ----------------
__global__ void o2_dot_k(const bf16* __restrict__ Y, const void* __restrict__ w,
                         const void* __restrict__ bias, const int* __restrict__ flag,
                         float* __restrict__ smap) {
    __shared__ float wl[576];
    int tid = threadIdx.x;
    int f = *flag;
    for (int c = tid; c < 576; c += 256) wl[c] = ld_in(w, f, c);
    __syncthreads();
    int wv = tid >> 6, lane = tid & 63;
    int pix = blockIdx.x * 4 + wv;
    const bf16* yp = Y + (size_t)pix * 576;
    float s = 0.f;
#pragma unroll
    for (int k = 0; k < 9; k++) {
        int c = k * 64 + lane;
        s += __bfloat162float(yp[c]) * wl[c];
    }
#pragma unroll
    for (int off = 32; off; off >>= 1) s += __shfl_xor(s, off, 64);
    if (lane == 0) smap[pix] = s + ld_in(bias, f, 0);
}

__global__ void upsample_k(const float* __restrict__ smap, void* __restrict__ out,
                           const int* __restrict__ flag) {
    int idx = blockIdx.x * 256 + threadIdx.x;   // 8*512*512 exact
    int b = idx >> 18;
    int ho = (idx >> 9) & 511;
    int wo = idx & 511;
    const float sc = 63.f / 511.f;              // align_corners=True
    float ys = ho * sc, xs = wo * sc;
    int y0 = (int)ys; float ty = ys - y0; int y1 = min(y0 + 1, 63);
    int x0 = (int)xs; float tx = xs - x0; int x1 = min(x0 + 1, 63);
    const float* sp = smap + (b << 12);
    float r0 = sp[y0 * 64 + x0] * (1.f - tx) + sp[y0 * 64 + x1] * tx;
    float r1 = sp[y1 * 64 + x0] * (1.f - tx) + sp[y1 * 64 + x1] * tx;
    float val = r0 * (1.f - ty) + r1 * ty;
    if (*flag) ((float*)out)[idx] = val;        // output dtype follows input dtype
    else       ((bf16*)out)[idx] = __float2bfloat16(val);
}

// ---------------- launch ----------------
extern "C" void kernel_launch(void* const* d_in, const int* in_sizes, int n_in,
                              void* d_out, int out_size, void* d_ws, size_t ws_size,
                              hipStream_t stream) {
    const void* coarse = d_in[0];
    const void* x22    = d_in[1];
    const void* x31    = d_in[2];
    const void* rawx   = d_in[3];
    // d_in[4]=w_pred, d_in[5]=b_pred : dead code in reference
    const void* dec_w = d_in[6];
    const void *dec_g = d_in[7], *dec_b = d_in[8], *dec_m = d_in[9], *dec_v = d_in[10];
    const void* cc_w = d_in[11];
    const void *cc_g = d_in[12], *cc_b = d_in[13], *cc_m = d_in[14], *cc_v = d_in[15];
    const void* o1_w = d_in[16];
    const void *o1_g = d_in[17], *o1_b = d_in[18], *o1_m = d_in[19], *o1_v = d_in[20];
    const void* o2_w = d_in[21];
    const void* o2_b = d_in[22];

    // chunk size G images, adaptive to ws_size (hedge vs small workspace)
    const size_t w_sz = (size_t)9 * 640 * 1632 * 2;     // 18,800,640
    int G = 2;
    for (;;) {
        size_t need = (size_t)G * 4356 * 576 * 2 + (size_t)G * 4356 * 1632 * 2
                    + w_sz + 16384 + 131072 + 64;
        if (need <= ws_size || G == 1) break;
        G = 1;
    }
    size_t xa_sz = (size_t)G * 4356 * 576 * 2;
    size_t xb_sz = (size_t)G * 4356 * 1632 * 2;

    char* ws = (char*)d_ws;
    bf16* Xa   = (bf16*)(ws);
    bf16* Xb   = (bf16*)(ws + xa_sz);
    bf16* Wbuf = (bf16*)(ws + xa_sz + xb_sz);
    float* sb  = (float*)(ws + xa_sz + xb_sz + w_sz);
    float* invDec = sb,        *betaDec = sb + 576;
    float* invCc  = sb + 1152, *betaCc  = sb + 1728;
    float* invO1  = sb + 2304, *betaO1  = sb + 2880;
    float* smap = (float*)(ws + xa_sz + xb_sz + w_sz + 16384);
    int* flag   = (int*)(ws + xa_sz + xb_sz + w_sz + 16384 + 131072);
    bf16* Yo1q = Xb;   // per-chunk o1 output (flat G*4096 x 576) aliases Xb

    detect_k<<<1, 64, 0, stream>>>(coarse, flag);
    scale_beta_k<<<3, 256, 0, stream>>>(dec_g, dec_b, dec_m, dec_v, flag, invDec, betaDec);
    scale_beta_k<<<3, 256, 0, stream>>>(cc_g, cc_b, cc_m, cc_v, flag, invCc, betaCc);
    scale_beta_k<<<3, 256, 0, stream>>>(o1_g, o1_b, o1_m, o1_v, flag, invO1, betaO1);

    const int nchunk = 8 / G;
    for (int q = 0; q < nchunk; q++) {
        const int b0 = q * G;
        zero_border_k<<<dim3(260, G), 256, 0, stream>>>(Xa, 576);
        zero_border_k<<<dim3(260, G), 256, 0, stream>>>(Xb, 1632);
        nchw_to_pnhwc_k<<<dim3(12, 64, G), 256, 0, stream>>>(coarse, Xa, flag, 384, 576, 0, b0);
        raw_patches_k<<<dim3(64, 3, G), 256, 0, stream>>>(rawx, Xa, flag, b0);
        nchw_to_pnhwc_k<<<dim3(24, 64, G), 256, 0, stream>>>(x22, Xb, flag, 768, 1632, 0, b0);
        nchw_to_pnhwc_k<<<dim3(9, 64, G), 256, 0, stream>>>(x31, Xb, flag, 288, 1632, 1344, b0);
        // dec: Xa(576) -> Xb channels 768..1343
        fold_w_k<<<dim3(3, 640, 9), 256, 0, stream>>>(dec_w, Wbuf, flag, 576, 1);
        conv3x3_mfma<<<dim3(G * 32, 5), 256, 0, stream>>>(Xa, Wbuf, invDec, betaDec, Xb, 576, 1632, 768, 1);
        // cc: Xb(1632) -> Xa(576)
        fold_w_k<<<dim3(7, 640, 9), 256, 0, stream>>>(cc_w, Wbuf, flag, 1632, 0);
        conv3x3_mfma<<<dim3(G * 32, 5), 256, 0, stream>>>(Xb, Wbuf, invCc, betaCc, Xa, 1632, 576, 0, 1);
        // o1: Xa(576) -> Yo1q flat (aliases Xb; Xb dead after cc read)
        fold_w_k<<<dim3(3, 640, 9), 256, 0, stream>>>(o1_w, Wbuf, flag, 576, 0);
        conv3x3_mfma<<<dim3(G * 32, 5), 256, 0, stream>>>(Xa, Wbuf, invO1, betaO1, Yo1q, 576, 576, 0, 0);
        // o2 1x1 conv -> smap slice
        o2_dot_k<<<G * 1024, 256, 0, stream>>>(Yo1q, o2_w, o2_b, flag, smap + (size_t)q * G * 4096);
    }
    upsample_k<<<8192, 256, 0, stream>>>(smap, d_out, flag);
}

// Round 4
// 2003.301 us; speedup vs baseline: 1.3878x; 1.3878x over previous
//
#include <hip/hip_runtime.h>
#include <hip/hip_bf16.h>
#include <stdint.h>

typedef __attribute__((ext_vector_type(8))) __bf16 bf16x8;
typedef __attribute__((ext_vector_type(8))) short short8;
typedef __attribute__((ext_vector_type(4))) float floatx4;
using bf16 = __hip_bfloat16;

#define DEVINL __device__ __forceinline__

typedef __attribute__((address_space(1))) const void gconst_void;
typedef __attribute__((address_space(3))) void lds_void;

DEVINL void gl2lds16(const void* g, void* l) {
    __builtin_amdgcn_global_load_lds((gconst_void*)g, (lds_void*)l, 16, 0, 0);
}

DEVINL unsigned short f2us(float x) {
    bf16 h = __float2bfloat16(x);
    return __builtin_bit_cast(unsigned short, h);
}
// flag==1: inputs are f32; flag==0: inputs are bf16
DEVINL float ld_in(const void* p, int f, size_t i) {
    return f ? ((const float*)p)[i] : __bfloat162float(((const bf16*)p)[i]);
}

// ---------------- dtype probe (confirmed r3: inputs are f32; keep hedge) ----------------
__global__ void detect_k(const void* x, int* flag) {
    if (threadIdx.x == 0) {
        const float* xf = (const float*)x;
        int good = 0;
        for (int i = 0; i < 64; i++) {
            float a = fabsf(xf[i]);
            if (a > 1e-8f && a < 100.f) good++;
        }
        *flag = (good >= 48) ? 1 : 0;
    }
}

// ---------------- prep kernels ----------------

// zero the 1-wide spatial border of a padded (G,66,66,C) NHWC buffer
__global__ void zero_border_k(bf16* buf, int C) {
    int cell = blockIdx.x;   // 0..259
    int b = blockIdx.y;      // local image
    int hp, wp;
    if (cell < 66)       { hp = 0;          wp = cell; }
    else if (cell < 132) { hp = 65;         wp = cell - 66; }
    else if (cell < 196) { hp = cell - 131; wp = 0; }
    else                 { hp = cell - 195; wp = 65; }
    unsigned short* p = (unsigned short*)buf + (size_t)(b * 4356 + hp * 66 + wp) * C;
    for (int c = threadIdx.x; c < C; c += 256) p[c] = 0;
}

// NCHW (B,Csrc,64,64) image (b0+bz) -> padded NHWC interior (local bz) at channel offset
__global__ void nchw_to_pnhwc_k(const void* __restrict__ src, bf16* __restrict__ dst,
                                const int* __restrict__ flag,
                                int Csrc, int dstC, int chanOff, int b0) {
    __shared__ unsigned short t[32][72];
    int c0 = blockIdx.x * 32, h = blockIdx.y, bz = blockIdx.z;
    int tid = threadIdx.x;
    {
        int c = tid >> 3, w8 = (tid & 7) * 8;
        size_t base = (((size_t)((b0 + bz) * Csrc + c0 + c)) * 64 + h) * 64 + w8;
        unsigned short* tp = &t[c][w8];
        if (*flag) {
            const float* sf = (const float*)src;
            float4 v0 = *(const float4*)(sf + base);
            float4 v1 = *(const float4*)(sf + base + 4);
            tp[0] = f2us(v0.x); tp[1] = f2us(v0.y); tp[2] = f2us(v0.z); tp[3] = f2us(v0.w);
            tp[4] = f2us(v1.x); tp[5] = f2us(v1.y); tp[6] = f2us(v1.z); tp[7] = f2us(v1.w);
        } else {
            uint4 v = *(const uint4*)((const unsigned short*)src + base);
            *(uint4*)tp = v;
        }
    }
    __syncthreads();
    {
        int w = tid >> 2, cq = (tid & 3) * 8;
        uint32_t p0 = t[cq + 0][w] | ((uint32_t)t[cq + 1][w] << 16);
        uint32_t p1 = t[cq + 2][w] | ((uint32_t)t[cq + 3][w] << 16);
        uint32_t p2 = t[cq + 4][w] | ((uint32_t)t[cq + 5][w] << 16);
        uint32_t p3 = t[cq + 6][w] | ((uint32_t)t[cq + 7][w] << 16);
        uint4 o; o.x = p0; o.y = p1; o.z = p2; o.w = p3;
        size_t off = ((size_t)(bz * 4356 + (h + 1) * 66 + (w + 1))) * dstC + chanOff + c0 + cq;
        *(uint4*)((unsigned short*)dst + off) = o;
    }
}

// raw_x (B,3,512,512) image (b0+bz) -> Xa channels [384+craw*64+gy*8+gx] (craw-major)
__global__ void raw_patches_k(const void* __restrict__ raw, bf16* __restrict__ Xa,
                              const int* __restrict__ flag, int b0) {
    __shared__ unsigned short t[8][520];
    int h = blockIdx.x, craw = blockIdx.y, bz = blockIdx.z;
    int tid = threadIdx.x;
    int f = *flag;
#pragma unroll
    for (int k = 0; k < 2; k++) {
        int s = tid + k * 256;
        int gy = s >> 6, seg = s & 63;
        size_t base = (((size_t)((b0 + bz) * 3 + craw) * 512) + gy * 64 + h) * 512 + seg * 8;
        unsigned short* tp = &t[gy][seg * 8];
        if (f) {
            const float* rf = (const float*)raw;
            float4 v0 = *(const float4*)(rf + base);
            float4 v1 = *(const float4*)(rf + base + 4);
            tp[0] = f2us(v0.x); tp[1] = f2us(v0.y); tp[2] = f2us(v0.z); tp[3] = f2us(v0.w);
            tp[4] = f2us(v1.x); tp[5] = f2us(v1.y); tp[6] = f2us(v1.z); tp[7] = f2us(v1.w);
        } else {
            uint4 v = *(const uint4*)((const unsigned short*)raw + base);
            *(uint4*)tp = v;
        }
    }
    __syncthreads();
#pragma unroll
    for (int k = 0; k < 2; k++) {
        int s = tid + k * 256;
        int w = s >> 3, gq = s & 7;
        uint32_t p0 = t[gq][0 * 64 + w] | ((uint32_t)t[gq][1 * 64 + w] << 16);
        uint32_t p1 = t[gq][2 * 64 + w] | ((uint32_t)t[gq][3 * 64 + w] << 16);
        uint32_t p2 = t[gq][4 * 64 + w] | ((uint32_t)t[gq][5 * 64 + w] << 16);
        uint32_t p3 = t[gq][6 * 64 + w] | ((uint32_t)t[gq][7 * 64 + w] << 16);
        uint4 o; o.x = p0; o.y = p1; o.z = p2; o.w = p3;
        size_t off = ((size_t)(bz * 4356 + (h + 1) * 66 + (w + 1))) * 576 + 384 + craw * 64 + gq * 8;
        *(uint4*)((unsigned short*)Xa + off) = o;
    }
}

// W[co][ci][3][3] -> Wp[kk][co_pad640][ci]; remap=1 permutes dec ci to craw-major order
__global__ void fold_w_k(const void* __restrict__ W, bf16* __restrict__ dst,
                         const int* __restrict__ flag, int Cin, int remap) {
    int ci = blockIdx.x * 256 + threadIdx.x;
    if (ci >= Cin) return;
    int co = blockIdx.y;  // 0..639
    int kk = blockIdx.z;  // 0..8
    unsigned short out = 0;
    if (co < 576) {
        int oc = ci;
        if (remap && ci >= 384) {
            int tt = ci - 384;
            int craw = tt >> 6, gy = (tt >> 3) & 7, gx = tt & 7;
            oc = 384 + gy * 24 + gx * 3 + craw;
        }
        size_t sidx = ((size_t)co * Cin + oc) * 9 + kk;
        out = (*flag) ? f2us(((const float*)W)[sidx]) : ((const unsigned short*)W)[sidx];
    }
    ((unsigned short*)dst)[((size_t)kk * 640 + co) * Cin + ci] = out;
}

// per-channel BN fold: inv = g/sqrt(v+eps), beta = b - m*inv
__global__ void scale_beta_k(const void* g, const void* b, const void* m, const void* v,
                             const int* __restrict__ flag, float* inv_out, float* beta_out) {
    int i = blockIdx.x * 256 + threadIdx.x;
    int f = *flag;
    if (i < 576) {
        float inv = ld_in(g, f, i) / sqrtf(ld_in(v, f, i) + 1e-5f);
        inv_out[i] = inv;
        beta_out[i] = ld_in(b, f, i) - ld_in(m, f, i) * inv;
    }
}

// ---------------- 3x3 conv as implicit GEMM (m97 structure), M = gridDim.x*128 ----------------
__global__ __launch_bounds__(256)
void conv3x3_mfma(const bf16* __restrict__ X, const bf16* __restrict__ Wp,
                  const float* __restrict__ inv, const float* __restrict__ beta,
                  bf16* __restrict__ dst, int Cin, int dstC, int chanOff, int dstPadded) {
    __shared__ __align__(16) bf16 Alds[128 * 32];
    __shared__ __align__(16) bf16 Blds[128 * 32];
    const int tid = threadIdx.x;
    const int wv = tid >> 6;
    const int lane = tid & 63;
    const int quad = lane >> 4;
    const int r16 = lane & 15;
    const int m0 = blockIdx.x * 128;
    const int n0 = blockIdx.y * 128;

    const int arow = tid >> 2;
    const int ach = (tid & 3) * 8;
    int abase1, abase2;
    {
        int r = m0 + arow;
        int bb = r >> 12, hh = (r >> 6) & 63, ww = r & 63;
        abase1 = (bb * 4356 + (hh + 1) * 66 + (ww + 1)) * Cin + ach;
        r += 64;
        bb = r >> 12; hh = (r >> 6) & 63; ww = r & 63;
        abase2 = (bb * 4356 + (hh + 1) * 66 + (ww + 1)) * Cin + ach;
    }
    const int bbase1 = (n0 + arow) * Cin + ach;
    const int bbase2 = bbase1 + 64 * Cin;

    bf16* aldsW1 = Alds + wv * 512;          // wave-uniform LDS base (HW adds lane*16B)
    bf16* aldsW2 = Alds + 2048 + wv * 512;
    bf16* bldsW1 = Blds + wv * 512;
    bf16* bldsW2 = Blds + 2048 + wv * 512;

    floatx4 acc[4][4];
    floatx4 zero = {0.f, 0.f, 0.f, 0.f};
#pragma unroll
    for (int i = 0; i < 4; i++)
#pragma unroll
        for (int j = 0; j < 4; j++) acc[i][j] = zero;

    const int mh = (wv & 1) * 64;
    const int nh = (wv >> 1) * 64;

    for (int kk = 0; kk < 9; kk++) {
        const int dh = kk / 3 - 1, dw = kk % 3 - 1;
        const int tap = (dh * 66 + dw) * Cin;
        const bf16* Ag1 = X + abase1 + tap;
        const bf16* Ag2 = X + abase2 + tap;
        const bf16* Bg1 = Wp + (size_t)kk * 640 * Cin + bbase1;
        const bf16* Bg2 = Wp + (size_t)kk * 640 * Cin + bbase2;
        for (int ci = 0; ci < Cin; ci += 32) {
            __syncthreads();
            gl2lds16(Ag1 + ci, aldsW1);
            gl2lds16(Ag2 + ci, aldsW2);
            gl2lds16(Bg1 + ci, bldsW1);
            gl2lds16(Bg2 + ci, bldsW2);
            __syncthreads();                  // vmcnt drained at barrier
            short8 af[4], bfr[4];
#pragma unroll
            for (int i = 0; i < 4; i++)
                af[i] = *(const short8*)(Alds + (mh + i * 16 + r16) * 32 + quad * 8);
#pragma unroll
            for (int j = 0; j < 4; j++)
                bfr[j] = *(const short8*)(Blds + (nh + j * 16 + r16) * 32 + quad * 8);
#pragma unroll
            for (int i = 0; i < 4; i++)
#pragma unroll
                for (int j = 0; j < 4; j++)
                    acc[i][j] = __builtin_amdgcn_mfma_f32_16x16x32_bf16(
                        __builtin_bit_cast(bf16x8, af[i]), __builtin_bit_cast(bf16x8, bfr[j]),
                        acc[i][j], 0, 0, 0);
        }
    }

    // epilogue: D[row=quad*4+r, col=lane&15] (verified m89/m91 layout)
    int ncol[4]; float sj[4], bj[4]; bool nval[4];
#pragma unroll
    for (int j = 0; j < 4; j++) {
        ncol[j] = n0 + nh + j * 16 + r16;
        nval[j] = ncol[j] < 576;
        sj[j] = nval[j] ? inv[ncol[j]] : 0.f;
        bj[j] = nval[j] ? beta[ncol[j]] : 0.f;
    }
#pragma unroll
    for (int i = 0; i < 4; i++) {
#pragma unroll
        for (int r = 0; r < 4; r++) {
            int row = m0 + mh + i * 16 + quad * 4 + r;
            int didx;
            if (dstPadded) {
                int bb = row >> 12, hh = (row >> 6) & 63, ww = row & 63;
                didx = (bb * 4356 + (hh + 1) * 66 + (ww + 1)) * dstC + chanOff;
            } else {
                didx = row * dstC + chanOff;
            }
#pragma unroll
            for (int j = 0; j < 4; j++)
                if (nval[j]) dst[didx + ncol[j]] = __float2bfloat16(acc[i][j][r] * sj[j] + bj[j]);
        }
    }
}

// ---------------- tail: 1x1 conv (576->1) + x8 bilinear upsample ----------------
__global__ void o2_dot_k(const bf16* __restrict__ Y, const void* __restrict__ w,
                         const void* __restrict__ bias, const int* __restrict__ flag,
                         float* __restrict__ smap) {
    __shared__ float wl[576];
    int tid = threadIdx.x;
    int f = *flag;
    for (int c = tid; c < 576; c += 256) wl[c] = ld_in(w, f, c);
    __syncthreads();
    int wv = tid >> 6, lane = tid & 63;
    int pix = blockIdx.x * 4 + wv;
    const bf16* yp = Y + (size_t)pix * 576;
    float s = 0.f;
#pragma unroll
    for (int k = 0; k < 9; k++) {
        int c = k * 64 + lane;
        s += __bfloat162float(yp[c]) * wl[c];
    }
#pragma unroll
    for (int off = 32; off; off >>= 1) s += __shfl_xor(s, off, 64);
    if (lane == 0) smap[pix] = s + ld_in(bias, f, 0);
}

__global__ void upsample_k(const float* __restrict__ smap, void* __restrict__ out,
                           const int* __restrict__ flag) {
    int idx = blockIdx.x * 256 + threadIdx.x;   // 8*512*512 exact
    int b = idx >> 18;
    int ho = (idx >> 9) & 511;
    int wo = idx & 511;
    const float sc = 63.f / 511.f;              // align_corners=True
    float ys = ho * sc, xs = wo * sc;
    int y0 = (int)ys; float ty = ys - y0; int y1 = min(y0 + 1, 63);
    int x0 = (int)xs; float tx = xs - x0; int x1 = min(x0 + 1, 63);
    const float* sp = smap + (b << 12);
    float r0 = sp[y0 * 64 + x0] * (1.f - tx) + sp[y0 * 64 + x1] * tx;
    float r1 = sp[y1 * 64 + x0] * (1.f - tx) + sp[y1 * 64 + x1] * tx;
    float val = r0 * (1.f - ty) + r1 * ty;
    if (*flag) ((float*)out)[idx] = val;        // output dtype follows input dtype
    else       ((bf16*)out)[idx] = __float2bfloat16(val);
}

// ---------------- launch ----------------
extern "C" void kernel_launch(void* const* d_in, const int* in_sizes, int n_in,
                              void* d_out, int out_size, void* d_ws, size_t ws_size,
                              hipStream_t stream) {
    const void* coarse = d_in[0];
    const void* x22    = d_in[1];
    const void* x31    = d_in[2];
    const void* rawx   = d_in[3];
    // d_in[4]=w_pred, d_in[5]=b_pred : dead code in reference
    const void* dec_w = d_in[6];
    const void *dec_g = d_in[7], *dec_b = d_in[8], *dec_m = d_in[9], *dec_v = d_in[10];
    const void* cc_w = d_in[11];
    const void *cc_g = d_in[12], *cc_b = d_in[13], *cc_m = d_in[14], *cc_v = d_in[15];
    const void* o1_w = d_in[16];
    const void *o1_g = d_in[17], *o1_b = d_in[18], *o1_m = d_in[19], *o1_v = d_in[20];
    const void* o2_w = d_in[21];
    const void* o2_b = d_in[22];

    // --- adaptive chunk ladder: prefer big G (occupancy), then once-packed weights ---
    const size_t wcc_sz  = (size_t)9 * 640 * 1632 * 2;   // 18,800,640
    const size_t wsm_sz  = (size_t)9 * 640 * 576 * 2;    // 6,635,520
    const size_t tail_sz = 16384 + 131072 + 256;         // sb + smap + flag
    int G = 8; int sepW = 1;
    for (;;) {
        size_t acts = (size_t)G * 4356 * (576 + 1632) * 2;
        if (acts + wcc_sz + 2 * wsm_sz + tail_sz <= ws_size) { sepW = 1; break; }
        if (acts + wcc_sz + tail_sz <= ws_size)              { sepW = 0; break; }
        if (G == 1) { sepW = 0; break; }
        G >>= 1;
    }
    size_t xa_sz = (size_t)G * 4356 * 576 * 2;
    size_t xb_sz = (size_t)G * 4356 * 1632 * 2;

    char* ws = (char*)d_ws;
    bf16* Xa   = (bf16*)(ws);
    bf16* Xb   = (bf16*)(ws + xa_sz);
    bf16* Wcc  = (bf16*)(ws + xa_sz + xb_sz);                      // shared slot if !sepW
    bf16* Wdec = sepW ? (bf16*)(ws + xa_sz + xb_sz + wcc_sz) : Wcc;
    bf16* Wo1  = sepW ? (bf16*)(ws + xa_sz + xb_sz + wcc_sz + wsm_sz) : Wcc;
    size_t wtot = wcc_sz + (sepW ? 2 * wsm_sz : 0);
    float* sb  = (float*)(ws + xa_sz + xb_sz + wtot);
    float* invDec = sb,        *betaDec = sb + 576;
    float* invCc  = sb + 1152, *betaCc  = sb + 1728;
    float* invO1  = sb + 2304, *betaO1  = sb + 2880;
    float* smap = (float*)(ws + xa_sz + xb_sz + wtot + 16384);
    int* flag   = (int*)(ws + xa_sz + xb_sz + wtot + 16384 + 131072);
    bf16* Yo1q = Xb;   // per-chunk o1 output (flat G*4096 x 576) aliases Xb

    detect_k<<<1, 64, 0, stream>>>(coarse, flag);
    scale_beta_k<<<3, 256, 0, stream>>>(dec_g, dec_b, dec_m, dec_v, flag, invDec, betaDec);
    scale_beta_k<<<3, 256, 0, stream>>>(cc_g, cc_b, cc_m, cc_v, flag, invCc, betaCc);
    scale_beta_k<<<3, 256, 0, stream>>>(o1_g, o1_b, o1_m, o1_v, flag, invO1, betaO1);
    if (sepW) {  // pack all weights once
        fold_w_k<<<dim3(3, 640, 9), 256, 0, stream>>>(dec_w, Wdec, flag, 576, 1);
        fold_w_k<<<dim3(7, 640, 9), 256, 0, stream>>>(cc_w, Wcc, flag, 1632, 0);
        fold_w_k<<<dim3(3, 640, 9), 256, 0, stream>>>(o1_w, Wo1, flag, 576, 0);
    }

    const int nchunk = 8 / G;
    for (int q = 0; q < nchunk; q++) {
        const int b0 = q * G;
        zero_border_k<<<dim3(260, G), 256, 0, stream>>>(Xa, 576);
        zero_border_k<<<dim3(260, G), 256, 0, stream>>>(Xb, 1632);
        nchw_to_pnhwc_k<<<dim3(12, 64, G), 256, 0, stream>>>(coarse, Xa, flag, 384, 576, 0, b0);
        raw_patches_k<<<dim3(64, 3, G), 256, 0, stream>>>(rawx, Xa, flag, b0);
        nchw_to_pnhwc_k<<<dim3(24, 64, G), 256, 0, stream>>>(x22, Xb, flag, 768, 1632, 0, b0);
        nchw_to_pnhwc_k<<<dim3(9, 64, G), 256, 0, stream>>>(x31, Xb, flag, 288, 1632, 1344, b0);
        // dec: Xa(576) -> Xb channels 768..1343
        if (!sepW) fold_w_k<<<dim3(3, 640, 9), 256, 0, stream>>>(dec_w, Wdec, flag, 576, 1);
        conv3x3_mfma<<<dim3(G * 32, 5), 256, 0, stream>>>(Xa, Wdec, invDec, betaDec, Xb, 576, 1632, 768, 1);
        // cc: Xb(1632) -> Xa(576)
        if (!sepW) fold_w_k<<<dim3(7, 640, 9), 256, 0, stream>>>(cc_w, Wcc, flag, 1632, 0);
        conv3x3_mfma<<<dim3(G * 32, 5), 256, 0, stream>>>(Xb, Wcc, invCc, betaCc, Xa, 1632, 576, 0, 1);
        // o1: Xa(576) -> Yo1q flat (aliases Xb; Xb dead after cc read)
        if (!sepW) fold_w_k<<<dim3(3, 640, 9), 256, 0, stream>>>(o1_w, Wo1, flag, 576, 0);
        conv3x3_mfma<<<dim3(G * 32, 5), 256, 0, stream>>>(Xa, Wo1, invO1, betaO1, Yo1q, 576, 576, 0, 0);
        // o2 1x1 conv -> smap slice
        o2_dot_k<<<G * 1024, 256, 0, stream>>>(Yo1q, o2_w, o2_b, flag, smap + (size_t)q * G * 4096);
    }
    upsample_k<<<8192, 256, 0, stream>>>(smap, d_out, flag);
}

// Round 5
// 1619.409 us; speedup vs baseline: 1.7168x; 1.2371x over previous
//
#include <hip/hip_runtime.h>
#include <hip/hip_bf16.h>
#include <stdint.h>

typedef __attribute__((ext_vector_type(8))) __bf16 bf16x8;
typedef __attribute__((ext_vector_type(8))) short short8;
typedef __attribute__((ext_vector_type(4))) float floatx4;
using bf16 = __hip_bfloat16;

#define DEVINL __device__ __forceinline__

typedef __attribute__((address_space(1))) const void gconst_void;
typedef __attribute__((address_space(3))) void lds_void;

DEVINL void gl2lds16(const void* g, void* l) {
    __builtin_amdgcn_global_load_lds((gconst_void*)g, (lds_void*)l, 16, 0, 0);
}

DEVINL unsigned short f2us(float x) {
    bf16 h = __float2bfloat16(x);
    return __builtin_bit_cast(unsigned short, h);
}
// flag==1: inputs are f32; flag==0: inputs are bf16
DEVINL float ld_in(const void* p, int f, size_t i) {
    return f ? ((const float*)p)[i] : __bfloat162float(((const bf16*)p)[i]);
}

// ---------------- dtype probe (confirmed r3: inputs are f32; keep hedge) ----------------
__global__ void detect_k(const void* x, int* flag) {
    if (threadIdx.x == 0) {
        const float* xf = (const float*)x;
        int good = 0;
        for (int i = 0; i < 64; i++) {
            float a = fabsf(xf[i]);
            if (a > 1e-8f && a < 100.f) good++;
        }
        *flag = (good >= 48) ? 1 : 0;
    }
}

// ---------------- prep kernels ----------------

__global__ void zero_border_k(bf16* buf, int C) {
    int cell = blockIdx.x;   // 0..259
    int b = blockIdx.y;
    int hp, wp;
    if (cell < 66)       { hp = 0;          wp = cell; }
    else if (cell < 132) { hp = 65;         wp = cell - 66; }
    else if (cell < 196) { hp = cell - 131; wp = 0; }
    else                 { hp = cell - 195; wp = 65; }
    unsigned short* p = (unsigned short*)buf + (size_t)(b * 4356 + hp * 66 + wp) * C;
    for (int c = threadIdx.x; c < C; c += 256) p[c] = 0;
}

__global__ void nchw_to_pnhwc_k(const void* __restrict__ src, bf16* __restrict__ dst,
                                const int* __restrict__ flag,
                                int Csrc, int dstC, int chanOff, int b0) {
    __shared__ unsigned short t[32][72];
    int c0 = blockIdx.x * 32, h = blockIdx.y, bz = blockIdx.z;
    int tid = threadIdx.x;
    {
        int c = tid >> 3, w8 = (tid & 7) * 8;
        size_t base = (((size_t)((b0 + bz) * Csrc + c0 + c)) * 64 + h) * 64 + w8;
        unsigned short* tp = &t[c][w8];
        if (*flag) {
            const float* sf = (const float*)src;
            float4 v0 = *(const float4*)(sf + base);
            float4 v1 = *(const float4*)(sf + base + 4);
            tp[0] = f2us(v0.x); tp[1] = f2us(v0.y); tp[2] = f2us(v0.z); tp[3] = f2us(v0.w);
            tp[4] = f2us(v1.x); tp[5] = f2us(v1.y); tp[6] = f2us(v1.z); tp[7] = f2us(v1.w);
        } else {
            uint4 v = *(const uint4*)((const unsigned short*)src + base);
            *(uint4*)tp = v;
        }
    }
    __syncthreads();
    {
        int w = tid >> 2, cq = (tid & 3) * 8;
        uint32_t p0 = t[cq + 0][w] | ((uint32_t)t[cq + 1][w] << 16);
        uint32_t p1 = t[cq + 2][w] | ((uint32_t)t[cq + 3][w] << 16);
        uint32_t p2 = t[cq + 4][w] | ((uint32_t)t[cq + 5][w] << 16);
        uint32_t p3 = t[cq + 6][w] | ((uint32_t)t[cq + 7][w] << 16);
        uint4 o; o.x = p0; o.y = p1; o.z = p2; o.w = p3;
        size_t off = ((size_t)(bz * 4356 + (h + 1) * 66 + (w + 1))) * dstC + chanOff + c0 + cq;
        *(uint4*)((unsigned short*)dst + off) = o;
    }
}

__global__ void raw_patches_k(const void* __restrict__ raw, bf16* __restrict__ Xa,
                              const int* __restrict__ flag, int b0) {
    __shared__ unsigned short t[8][520];
    int h = blockIdx.x, craw = blockIdx.y, bz = blockIdx.z;
    int tid = threadIdx.x;
    int f = *flag;
#pragma unroll
    for (int k = 0; k < 2; k++) {
        int s = tid + k * 256;
        int gy = s >> 6, seg = s & 63;
        size_t base = (((size_t)((b0 + bz) * 3 + craw) * 512) + gy * 64 + h) * 512 + seg * 8;
        unsigned short* tp = &t[gy][seg * 8];
        if (f) {
            const float* rf = (const float*)raw;
            float4 v0 = *(const float4*)(rf + base);
            float4 v1 = *(const float4*)(rf + base + 4);
            tp[0] = f2us(v0.x); tp[1] = f2us(v0.y); tp[2] = f2us(v0.z); tp[3] = f2us(v0.w);
            tp[4] = f2us(v1.x); tp[5] = f2us(v1.y); tp[6] = f2us(v1.z); tp[7] = f2us(v1.w);
        } else {
            uint4 v = *(const uint4*)((const unsigned short*)raw + base);
            *(uint4*)tp = v;
        }
    }
    __syncthreads();
#pragma unroll
    for (int k = 0; k < 2; k++) {
        int s = tid + k * 256;
        int w = s >> 3, gq = s & 7;
        uint32_t p0 = t[gq][0 * 64 + w] | ((uint32_t)t[gq][1 * 64 + w] << 16);
        uint32_t p1 = t[gq][2 * 64 + w] | ((uint32_t)t[gq][3 * 64 + w] << 16);
        uint32_t p2 = t[gq][4 * 64 + w] | ((uint32_t)t[gq][5 * 64 + w] << 16);
        uint32_t p3 = t[gq][6 * 64 + w] | ((uint32_t)t[gq][7 * 64 + w] << 16);
        uint4 o; o.x = p0; o.y = p1; o.z = p2; o.w = p3;
        size_t off = ((size_t)(bz * 4356 + (h + 1) * 66 + (w + 1))) * 576 + 384 + craw * 64 + gq * 8;
        *(uint4*)((unsigned short*)Xa + off) = o;
    }
}

__global__ void fold_w_k(const void* __restrict__ W, bf16* __restrict__ dst,
                         const int* __restrict__ flag, int Cin, int remap) {
    int ci = blockIdx.x * 256 + threadIdx.x;
    if (ci >= Cin) return;
    int co = blockIdx.y;  // 0..639
    int kk = blockIdx.z;  // 0..8
    unsigned short out = 0;
    if (co < 576) {
        int oc = ci;
        if (remap && ci >= 384) {
            int tt = ci - 384;
            int craw = tt >> 6, gy = (tt >> 3) & 7, gx = tt & 7;
            oc = 384 + gy * 24 + gx * 3 + craw;
        }
        size_t sidx = ((size_t)co * Cin + oc) * 9 + kk;
        out = (*flag) ? f2us(((const float*)W)[sidx]) : ((const unsigned short*)W)[sidx];
    }
    ((unsigned short*)dst)[((size_t)kk * 640 + co) * Cin + ci] = out;
}

__global__ void scale_beta_k(const void* g, const void* b, const void* m, const void* v,
                             const int* __restrict__ flag, float* inv_out, float* beta_out) {
    int i = blockIdx.x * 256 + threadIdx.x;
    int f = *flag;
    if (i < 576) {
        float inv = ld_in(g, f, i) / sqrtf(ld_in(v, f, i) + 1e-5f);
        inv_out[i] = inv;
        beta_out[i] = ld_in(b, f, i) - ld_in(m, f, i) * inv;
    }
}

// ---------------- 3x3 conv, implicit GEMM, BK=64, XOR-swizzled LDS ----------------
// LDS[row][c16] = Global[row][c16 ^ (row&7)]  (c16 = 16B chunk index, 8 per 64-hw row)
// -> ds_read_b128 fragment reads are bank-conflict-free (2-way max, free per m136).
__global__ __launch_bounds__(256)
void conv3x3_mfma(const bf16* __restrict__ X, const bf16* __restrict__ Wp,
                  const float* __restrict__ inv, const float* __restrict__ beta,
                  bf16* __restrict__ dst, int Cin, int dstC, int chanOff, int dstPadded) {
    __shared__ __align__(16) bf16 Alds[128 * 64];   // 16 KB
    __shared__ __align__(16) bf16 Blds[128 * 64];   // 16 KB
    const int tid = threadIdx.x;
    const int wv = tid >> 6;
    const int lane = tid & 63;
    const int quad = lane >> 4;
    const int r16 = lane & 15;
    const int m0 = blockIdx.x * 128;
    const int n0 = blockIdx.y * 128;

    // ---- full BK=64 staging geometry: slot i=q*256+tid, row=i>>3=rbase+32q, c_l=tid&7 ----
    const int rbase = tid >> 3;                       // 0..31
    const int cg = ((tid & 7) ^ (rbase & 7)) * 8;     // swizzled source chunk (halfwords)
    int aF[4], bF[4];
#pragma unroll
    for (int q = 0; q < 4; q++) {
        int r = m0 + rbase + 32 * q;
        int bb = r >> 12, hh = (r >> 6) & 63, ww = r & 63;
        aF[q] = (bb * 4356 + (hh + 1) * 66 + (ww + 1)) * Cin + cg;
        bF[q] = (n0 + rbase + 32 * q) * Cin + cg;
    }
    // ---- half BK=32 staging (remainder, linear layout): slot i=q*256+tid, row=i>>2 ----
    const int rbh = tid >> 2;                         // 0..63
    int aH[2], bH[2];
#pragma unroll
    for (int q = 0; q < 2; q++) {
        int r = m0 + rbh + 64 * q;
        int bb = r >> 12, hh = (r >> 6) & 63, ww = r & 63;
        aH[q] = (bb * 4356 + (hh + 1) * 66 + (ww + 1)) * Cin + (tid & 3) * 8;
        bH[q] = (n0 + rbh + 64 * q) * Cin + (tid & 3) * 8;
    }

    // wave-uniform LDS staging bases (HW adds lane*16B)
    bf16* aldsW[4]; bf16* bldsW[4];
#pragma unroll
    for (int q = 0; q < 4; q++) {
        aldsW[q] = Alds + q * 2048 + wv * 512;
        bldsW[q] = Blds + q * 2048 + wv * 512;
    }

    floatx4 acc[4][4];
    floatx4 zero = {0.f, 0.f, 0.f, 0.f};
#pragma unroll
    for (int i = 0; i < 4; i++)
#pragma unroll
        for (int j = 0; j < 4; j++) acc[i][j] = zero;

    const int mh = (wv & 1) * 64;
    const int nh = (wv >> 1) * 64;
    // swizzled fragment-read chunk offsets (halfwords) for kq=0,1
    const int sw0 = (quad ^ (r16 & 7)) * 8;
    const int sw1 = ((quad + 4) ^ (r16 & 7)) * 8;

    const int nfull = Cin >> 6;           // # of BK=64 iterations per tap
    const int rem = Cin & 63;             // 0 or 32

    for (int kk = 0; kk < 9; kk++) {
        const int dh = kk / 3 - 1, dw = kk % 3 - 1;
        const int tap = (dh * 66 + dw) * Cin;
        const bf16* Wk = Wp + (size_t)kk * 640 * Cin;
        int ci = 0;
        for (int f = 0; f < nfull; f++, ci += 64) {
            __syncthreads();
#pragma unroll
            for (int q = 0; q < 4; q++) gl2lds16(X + aF[q] + tap + ci, aldsW[q]);
#pragma unroll
            for (int q = 0; q < 4; q++) gl2lds16(Wk + bF[q] + ci, bldsW[q]);
            __syncthreads();              // vmcnt drained at barrier
#pragma unroll
            for (int kq = 0; kq < 2; kq++) {
                const int sw = kq ? sw1 : sw0;
                short8 af[4], bfr[4];
#pragma unroll
                for (int i = 0; i < 4; i++)
                    af[i] = *(const short8*)(Alds + (mh + i * 16 + r16) * 64 + sw);
#pragma unroll
                for (int j = 0; j < 4; j++)
                    bfr[j] = *(const short8*)(Blds + (nh + j * 16 + r16) * 64 + sw);
#pragma unroll
                for (int i = 0; i < 4; i++)
#pragma unroll
                    for (int j = 0; j < 4; j++)
                        acc[i][j] = __builtin_amdgcn_mfma_f32_16x16x32_bf16(
                            __builtin_bit_cast(bf16x8, af[i]), __builtin_bit_cast(bf16x8, bfr[j]),
                            acc[i][j], 0, 0, 0);
            }
        }
        if (rem) {  // rem == 32: linear [128][32hw] layout in the same LDS arrays
            __syncthreads();
#pragma unroll
            for (int q = 0; q < 2; q++) gl2lds16(X + aH[q] + tap + ci, aldsW[q]);
#pragma unroll
            for (int q = 0; q < 2; q++) gl2lds16(Wk + bH[q] + ci, bldsW[q]);
            __syncthreads();
            short8 af[4], bfr[4];
#pragma unroll
            for (int i = 0; i < 4; i++)
                af[i] = *(const short8*)(Alds + (mh + i * 16 + r16) * 32 + quad * 8);
#pragma unroll
            for (int j = 0; j < 4; j++)
                bfr[j] = *(const short8*)(Blds + (nh + j * 16 + r16) * 32 + quad * 8);
#pragma unroll
            for (int i = 0; i < 4; i++)
#pragma unroll
                for (int j = 0; j < 4; j++)
                    acc[i][j] = __builtin_amdgcn_mfma_f32_16x16x32_bf16(
                        __builtin_bit_cast(bf16x8, af[i]), __builtin_bit_cast(bf16x8, bfr[j]),
                        acc[i][j], 0, 0, 0);
        }
    }

    // epilogue: D[row=quad*4+r, col=lane&15] (verified m89/m91 layout)
    int ncol[4]; float sj[4], bj[4]; bool nval[4];
#pragma unroll
    for (int j = 0; j < 4; j++) {
        ncol[j] = n0 + nh + j * 16 + r16;
        nval[j] = ncol[j] < 576;
        sj[j] = nval[j] ? inv[ncol[j]] : 0.f;
        bj[j] = nval[j] ? beta[ncol[j]] : 0.f;
    }
#pragma unroll
    for (int i = 0; i < 4; i++) {
#pragma unroll
        for (int r = 0; r < 4; r++) {
            int row = m0 + mh + i * 16 + quad * 4 + r;
            int didx;
            if (dstPadded) {
                int bb = row >> 12, hh = (row >> 6) & 63, ww = row & 63;
                didx = (bb * 4356 + (hh + 1) * 66 + (ww + 1)) * dstC + chanOff;
            } else {
                didx = row * dstC + chanOff;
            }
#pragma unroll
            for (int j = 0; j < 4; j++)
                if (nval[j]) dst[didx + ncol[j]] = __float2bfloat16(acc[i][j][r] * sj[j] + bj[j]);
        }
    }
}

// ---------------- tail: 1x1 conv (576->1) + x8 bilinear upsample ----------------
__global__ void o2_dot_k(const bf16* __restrict__ Y, const void* __restrict__ w,
                         const void* __restrict__ bias, const int* __restrict__ flag,
                         float* __restrict__ smap) {
    __shared__ float wl[576];
    int tid = threadIdx.x;
    int f = *flag;
    for (int c = tid; c < 576; c += 256) wl[c] = ld_in(w, f, c);
    __syncthreads();
    int wv = tid >> 6, lane = tid & 63;
    int pix = blockIdx.x * 4 + wv;
    const bf16* yp = Y + (size_t)pix * 576;
    float s = 0.f;
#pragma unroll
    for (int k = 0; k < 9; k++) {
        int c = k * 64 + lane;
        s += __bfloat162float(yp[c]) * wl[c];
    }
#pragma unroll
    for (int off = 32; off; off >>= 1) s += __shfl_xor(s, off, 64);
    if (lane == 0) smap[pix] = s + ld_in(bias, f, 0);
}

__global__ void upsample_k(const float* __restrict__ smap, void* __restrict__ out,
                           const int* __restrict__ flag) {
    int idx = blockIdx.x * 256 + threadIdx.x;   // 8*512*512 exact
    int b = idx >> 18;
    int ho = (idx >> 9) & 511;
    int wo = idx & 511;
    const float sc = 63.f / 511.f;              // align_corners=True
    float ys = ho * sc, xs = wo * sc;
    int y0 = (int)ys; float ty = ys - y0; int y1 = min(y0 + 1, 63);
    int x0 = (int)xs; float tx = xs - x0; int x1 = min(x0 + 1, 63);
    const float* sp = smap + (b << 12);
    float r0 = sp[y0 * 64 + x0] * (1.f - tx) + sp[y0 * 64 + x1] * tx;
    float r1 = sp[y1 * 64 + x0] * (1.f - tx) + sp[y1 * 64 + x1] * tx;
    float val = r0 * (1.f - ty) + r1 * ty;
    if (*flag) ((float*)out)[idx] = val;
    else       ((bf16*)out)[idx] = __float2bfloat16(val);
}

// ---------------- launch ----------------
extern "C" void kernel_launch(void* const* d_in, const int* in_sizes, int n_in,
                              void* d_out, int out_size, void* d_ws, size_t ws_size,
                              hipStream_t stream) {
    const void* coarse = d_in[0];
    const void* x22    = d_in[1];
    const void* x31    = d_in[2];
    const void* rawx   = d_in[3];
    // d_in[4]=w_pred, d_in[5]=b_pred : dead code in reference
    const void* dec_w = d_in[6];
    const void *dec_g = d_in[7], *dec_b = d_in[8], *dec_m = d_in[9], *dec_v = d_in[10];
    const void* cc_w = d_in[11];
    const void *cc_g = d_in[12], *cc_b = d_in[13], *cc_m = d_in[14], *cc_v = d_in[15];
    const void* o1_w = d_in[16];
    const void *o1_g = d_in[17], *o1_b = d_in[18], *o1_m = d_in[19], *o1_v = d_in[20];
    const void* o2_w = d_in[21];
    const void* o2_b = d_in[22];

    // adaptive chunk ladder (r4 confirmed G=8 + sepW fits)
    const size_t wcc_sz  = (size_t)9 * 640 * 1632 * 2;
    const size_t wsm_sz  = (size_t)9 * 640 * 576 * 2;
    const size_t tail_sz = 16384 + 131072 + 256;
    int G = 8; int sepW = 1;
    for (;;) {
        size_t acts = (size_t)G * 4356 * (576 + 1632) * 2;
        if (acts + wcc_sz + 2 * wsm_sz + tail_sz <= ws_size) { sepW = 1; break; }
        if (acts + wcc_sz + tail_sz <= ws_size)              { sepW = 0; break; }
        if (G == 1) { sepW = 0; break; }
        G >>= 1;
    }
    size_t xa_sz = (size_t)G * 4356 * 576 * 2;
    size_t xb_sz = (size_t)G * 4356 * 1632 * 2;

    char* ws = (char*)d_ws;
    bf16* Xa   = (bf16*)(ws);
    bf16* Xb   = (bf16*)(ws + xa_sz);
    bf16* Wcc  = (bf16*)(ws + xa_sz + xb_sz);
    bf16* Wdec = sepW ? (bf16*)(ws + xa_sz + xb_sz + wcc_sz) : Wcc;
    bf16* Wo1  = sepW ? (bf16*)(ws + xa_sz + xb_sz + wcc_sz + wsm_sz) : Wcc;
    size_t wtot = wcc_sz + (sepW ? 2 * wsm_sz : 0);
    float* sb  = (float*)(ws + xa_sz + xb_sz + wtot);
    float* invDec = sb,        *betaDec = sb + 576;
    float* invCc  = sb + 1152, *betaCc  = sb + 1728;
    float* invO1  = sb + 2304, *betaO1  = sb + 2880;
    float* smap = (float*)(ws + xa_sz + xb_sz + wtot + 16384);
    int* flag   = (int*)(ws + xa_sz + xb_sz + wtot + 16384 + 131072);
    bf16* Yo1q = Xb;

    detect_k<<<1, 64, 0, stream>>>(coarse, flag);
    scale_beta_k<<<3, 256, 0, stream>>>(dec_g, dec_b, dec_m, dec_v, flag, invDec, betaDec);
    scale_beta_k<<<3, 256, 0, stream>>>(cc_g, cc_b, cc_m, cc_v, flag, invCc, betaCc);
    scale_beta_k<<<3, 256, 0, stream>>>(o1_g, o1_b, o1_m, o1_v, flag, invO1, betaO1);
    if (sepW) {
        fold_w_k<<<dim3(3, 640, 9), 256, 0, stream>>>(dec_w, Wdec, flag, 576, 1);
        fold_w_k<<<dim3(7, 640, 9), 256, 0, stream>>>(cc_w, Wcc, flag, 1632, 0);
        fold_w_k<<<dim3(3, 640, 9), 256, 0, stream>>>(o1_w, Wo1, flag, 576, 0);
    }

    const int nchunk = 8 / G;
    for (int q = 0; q < nchunk; q++) {
        const int b0 = q * G;
        zero_border_k<<<dim3(260, G), 256, 0, stream>>>(Xa, 576);
        zero_border_k<<<dim3(260, G), 256, 0, stream>>>(Xb, 1632);
        nchw_to_pnhwc_k<<<dim3(12, 64, G), 256, 0, stream>>>(coarse, Xa, flag, 384, 576, 0, b0);
        raw_patches_k<<<dim3(64, 3, G), 256, 0, stream>>>(rawx, Xa, flag, b0);
        nchw_to_pnhwc_k<<<dim3(24, 64, G), 256, 0, stream>>>(x22, Xb, flag, 768, 1632, 0, b0);
        nchw_to_pnhwc_k<<<dim3(9, 64, G), 256, 0, stream>>>(x31, Xb, flag, 288, 1632, 1344, b0);
        if (!sepW) fold_w_k<<<dim3(3, 640, 9), 256, 0, stream>>>(dec_w, Wdec, flag, 576, 1);
        conv3x3_mfma<<<dim3(G * 32, 5), 256, 0, stream>>>(Xa, Wdec, invDec, betaDec, Xb, 576, 1632, 768, 1);
        if (!sepW) fold_w_k<<<dim3(7, 640, 9), 256, 0, stream>>>(cc_w, Wcc, flag, 1632, 0);
        conv3x3_mfma<<<dim3(G * 32, 5), 256, 0, stream>>>(Xb, Wcc, invCc, betaCc, Xa, 1632, 576, 0, 1);
        if (!sepW) fold_w_k<<<dim3(3, 640, 9), 256, 0, stream>>>(o1_w, Wo1, flag, 576, 0);
        conv3x3_mfma<<<dim3(G * 32, 5), 256, 0, stream>>>(Xa, Wo1, invO1, betaO1, Yo1q, 576, 576, 0, 0);
        o2_dot_k<<<G * 1024, 256, 0, stream>>>(Yo1q, o2_w, o2_b, flag, smap + (size_t)q * G * 4096);
    }
    upsample_k<<<8192, 256, 0, stream>>>(smap, d_out, flag);
}